// Round 3
// baseline (1122.467 us; speedup 1.0000x reference)
//
#include <hip/hip_runtime.h>
#include <math.h>

#define N_NODES 100000
#define N_EDGES 1600000
#define IN_CH 256
#define HID_CH 128
#define OUT_CH 64
#define NBLK_SCAN ((N_NODES + 255) / 256)   // 391
#define NB_BUCKETS 1024                     // used: ceil(100000/128) = 782

typedef short s16x8 __attribute__((ext_vector_type(8)));
typedef unsigned short u16x8 __attribute__((ext_vector_type(8)));
typedef float f32x4 __attribute__((ext_vector_type(4)));

__device__ __forceinline__ float bf2f(unsigned short u) {
    union { unsigned int i; float f; } v;
    v.i = ((unsigned int)u) << 16;
    return v.f;
}
__device__ __forceinline__ unsigned short f2bf(float f) {
    union { float f; unsigned int i; } v;
    v.f = f;
    unsigned int u = v.i;
    return (unsigned short)((u + 0x7FFFu + ((u >> 16) & 1u)) >> 16);  // RNE
}

// ---------------- zero / degree+bucket count ----------------

__global__ void k_zero_int(int* __restrict__ p, int n) {
    int i = blockIdx.x * blockDim.x + threadIdx.x;
    if (i < n) p[i] = 0;
}

// deg[dst]++ and bcount[dst>>7]++
__global__ void k_count2(const int* __restrict__ dst, int* __restrict__ deg,
                         int* __restrict__ bcount) {
    int e = blockIdx.x * blockDim.x + threadIdx.x;
    if (e >= N_EDGES) return;
    int d = dst[e];
    atomicAdd(&deg[d], 1);
    atomicAdd(&bcount[d >> 7], 1);
}

__global__ void k_dinv_cursor(const int* __restrict__ deg, const int* __restrict__ rowoff,
                              float* __restrict__ dinv, int* __restrict__ cursor) {
    int i = blockIdx.x * blockDim.x + threadIdx.x;
    if (i >= N_NODES) return;
    dinv[i] = rsqrtf((float)deg[i] + 1.0f);
    cursor[i] = rowoff[i];
}

// ---------------- exclusive prefix scan over deg -> rowoff ----------------

__global__ void k_scan_block(const int* __restrict__ deg, int* __restrict__ excl,
                             int* __restrict__ bsums) {
    __shared__ int tmp[256];
    int i = blockIdx.x * 256 + threadIdx.x;
    int v = (i < N_NODES) ? deg[i] : 0;
    tmp[threadIdx.x] = v;
    __syncthreads();
    for (int off = 1; off < 256; off <<= 1) {
        int t = (threadIdx.x >= off) ? tmp[threadIdx.x - off] : 0;
        __syncthreads();
        tmp[threadIdx.x] += t;
        __syncthreads();
    }
    if (i < N_NODES) excl[i] = tmp[threadIdx.x] - v;
    if (threadIdx.x == 255) bsums[blockIdx.x] = tmp[255];
}

__global__ void k_scan_bsums(int* __restrict__ bsums) {  // single block of 512
    __shared__ int tmp[512];
    int v = (threadIdx.x < NBLK_SCAN) ? bsums[threadIdx.x] : 0;
    tmp[threadIdx.x] = v;
    __syncthreads();
    for (int off = 1; off < 512; off <<= 1) {
        int t = (threadIdx.x >= off) ? tmp[threadIdx.x - off] : 0;
        __syncthreads();
        tmp[threadIdx.x] += t;
        __syncthreads();
    }
    if (threadIdx.x < NBLK_SCAN) bsums[threadIdx.x] = tmp[threadIdx.x] - v;
}

__global__ void k_scan_add(int* __restrict__ excl, const int* __restrict__ bsums) {
    int i = blockIdx.x * 256 + threadIdx.x;
    if (i < N_NODES) excl[i] += bsums[blockIdx.x];
}

// exclusive scan over bucket counts -> bcursor (single block of 1024)
__global__ void k_scan_buckets(const int* __restrict__ bcount, int* __restrict__ bcursor) {
    __shared__ int tmp[NB_BUCKETS];
    int v = (threadIdx.x < NB_BUCKETS) ? bcount[threadIdx.x] : 0;
    tmp[threadIdx.x] = v;
    __syncthreads();
    for (int off = 1; off < NB_BUCKETS; off <<= 1) {
        int t = (threadIdx.x >= off) ? tmp[threadIdx.x - off] : 0;
        __syncthreads();
        tmp[threadIdx.x] += t;
        __syncthreads();
    }
    if (threadIdx.x < NB_BUCKETS) bcursor[threadIdx.x] = tmp[threadIdx.x] - v;
}

// ---------------- bucketed CSR build ----------------

// pass B: scatter (src,dst) int2 into dst-bucket-contiguous regions
__global__ void k_bucket_scatter(const int* __restrict__ src, const int* __restrict__ dst,
                                 int* __restrict__ bcursor, int2* __restrict__ bsorted) {
    int e = blockIdx.x * blockDim.x + threadIdx.x;
    if (e >= N_EDGES) return;
    int s = src[e], d = dst[e];
    int pos = atomicAdd(&bcursor[d >> 7], 1);
    bsorted[pos] = make_int2(s, d);
}

// pass C: sequential read of bucket-sorted edges, scatter src into csr rows
__global__ void k_fill_csr2(const int2* __restrict__ bsorted, int* __restrict__ cursor,
                            int* __restrict__ csr_src) {
    int e = blockIdx.x * blockDim.x + threadIdx.x;
    if (e >= N_EDGES) return;
    int2 v = bsorted[e];
    int pos = atomicAdd(&cursor[v.y], 1);
    csr_src[pos] = v.x;
}

// ---------------- W transpose+convert: WT[n][k] = bf16(W[k][n]) ----------------

template <int K, int N>
__global__ void k_wt(const float* __restrict__ W, unsigned short* __restrict__ WT) {
    int t = blockIdx.x * blockDim.x + threadIdx.x;
    if (t >= K * N) return;
    int n = t / K;
    int k = t % K;
    WT[t] = f2bf(W[(size_t)k * N + n]);
}

// ---------------- GEMM1: hs1[m][n] = bf16( dinv[m] * sum_k x[m][k] W1[k][n] ) ----------------
// MFMA 16x16x32 bf16, LDS-free. Block=256 (4 waves), each wave: 16 rows x 128 cols.
__global__ __launch_bounds__(256) void k_gemm1(const float* __restrict__ x,
                                               const unsigned short* __restrict__ W1T,
                                               const float* __restrict__ dinv,
                                               unsigned short* __restrict__ hs1) {
    int tid = threadIdx.x;
    int w = tid >> 6;
    int lane = tid & 63;
    int l15 = lane & 15;
    int lhi = lane >> 4;           // 0..3
    int m0 = blockIdx.x * 64 + w * 16;

    f32x4 acc[8] = {};

    int arow = m0 + l15;
    bool avalid = arow < N_NODES;
    const float* ap = x + (size_t)arow * IN_CH + lhi * 8;

    #pragma unroll
    for (int k0 = 0; k0 < IN_CH; k0 += 32) {
        s16x8 af = {};
        if (avalid) {
            float4 a0 = *reinterpret_cast<const float4*>(ap + k0);
            float4 a1 = *reinterpret_cast<const float4*>(ap + k0 + 4);
            af[0] = (short)f2bf(a0.x); af[1] = (short)f2bf(a0.y);
            af[2] = (short)f2bf(a0.z); af[3] = (short)f2bf(a0.w);
            af[4] = (short)f2bf(a1.x); af[5] = (short)f2bf(a1.y);
            af[6] = (short)f2bf(a1.z); af[7] = (short)f2bf(a1.w);
        }
        #pragma unroll
        for (int nt = 0; nt < 8; ++nt) {
            s16x8 bf = *reinterpret_cast<const s16x8*>(
                W1T + (size_t)(nt * 16 + l15) * IN_CH + k0 + lhi * 8);
            acc[nt] = __builtin_amdgcn_mfma_f32_16x16x32_bf16(af, bf, acc[nt], 0, 0, 0);
        }
    }

    // epilogue: D row = lhi*4 + r, col = l15
    float dv[4];
    int rb = m0 + lhi * 4;
    #pragma unroll
    for (int r = 0; r < 4; ++r) dv[r] = (rb + r < N_NODES) ? dinv[rb + r] : 0.0f;
    #pragma unroll
    for (int nt = 0; nt < 8; ++nt) {
        #pragma unroll
        for (int r = 0; r < 4; ++r) {
            int row = rb + r;
            if (row < N_NODES)
                hs1[(size_t)row * HID_CH + nt * 16 + l15] = f2bf(dv[r] * acc[nt][r]);
        }
    }
}

// ---------------- GEMM2: hs2[m][n] = bf16( dinv[m] * sum_k h1r[m][k] W2[k][n] ) ----------------
// A already bf16. Block=256 (4 waves), wave: 16 rows x 64 cols.
__global__ __launch_bounds__(256) void k_gemm2(const unsigned short* __restrict__ h1r,
                                               const unsigned short* __restrict__ W2T,
                                               const float* __restrict__ dinv,
                                               unsigned short* __restrict__ hs2) {
    int tid = threadIdx.x;
    int w = tid >> 6;
    int lane = tid & 63;
    int l15 = lane & 15;
    int lhi = lane >> 4;
    int m0 = blockIdx.x * 64 + w * 16;

    f32x4 acc[4] = {};

    int arow = m0 + l15;
    bool avalid = arow < N_NODES;
    const unsigned short* ap = h1r + (size_t)arow * HID_CH + lhi * 8;

    #pragma unroll
    for (int k0 = 0; k0 < HID_CH; k0 += 32) {
        s16x8 af = {};
        if (avalid) af = *reinterpret_cast<const s16x8*>(ap + k0);
        #pragma unroll
        for (int nt = 0; nt < 4; ++nt) {
            s16x8 bf = *reinterpret_cast<const s16x8*>(
                W2T + (size_t)(nt * 16 + l15) * HID_CH + k0 + lhi * 8);
            acc[nt] = __builtin_amdgcn_mfma_f32_16x16x32_bf16(af, bf, acc[nt], 0, 0, 0);
        }
    }

    float dv[4];
    int rb = m0 + lhi * 4;
    #pragma unroll
    for (int r = 0; r < 4; ++r) dv[r] = (rb + r < N_NODES) ? dinv[rb + r] : 0.0f;
    #pragma unroll
    for (int nt = 0; nt < 4; ++nt) {
        #pragma unroll
        for (int r = 0; r < 4; ++r) {
            int row = rb + r;
            if (row < N_NODES)
                hs2[(size_t)row * OUT_CH + nt * 16 + l15] = f2bf(dv[r] * acc[nt][r]);
        }
    }
}

// ---------------- gather aggregation (bf16 rows, fp32 accum) ----------------
// out[d,:] = bf16( [relu]( dinv[d] * (hs[d,:] + sum_{s in row d} hs[s,:]) + b ) )
template <int C, bool RELU>
__global__ __launch_bounds__(256) void k_gather_agg(const int* __restrict__ rowoff,
                                                    const int* __restrict__ csr_src,
                                                    const unsigned short* __restrict__ hs,
                                                    const float* __restrict__ dinv,
                                                    const float* __restrict__ b,
                                                    unsigned short* __restrict__ outp) {
    constexpr int TPN = C / 8;        // lanes per node, 16B (8 bf16) each
    constexpr int NPB = 256 / TPN;
    int t = threadIdx.x;
    int node = blockIdx.x * NPB + t / TPN;
    int q = t % TPN;
    if (node >= N_NODES) return;

    int beg = rowoff[node];
    int end = (node + 1 < N_NODES) ? rowoff[node + 1] : N_EDGES;

    float acc[8];
    {
        u16x8 sv = *reinterpret_cast<const u16x8*>(&hs[(size_t)node * C + q * 8]);
        #pragma unroll
        for (int j = 0; j < 8; ++j) acc[j] = bf2f(sv[j]);
    }

    int i = beg;
    for (; i + 1 < end; i += 2) {
        int s0 = csr_src[i];
        int s1 = csr_src[i + 1];
        u16x8 v0 = *reinterpret_cast<const u16x8*>(&hs[(size_t)s0 * C + q * 8]);
        u16x8 v1 = *reinterpret_cast<const u16x8*>(&hs[(size_t)s1 * C + q * 8]);
        #pragma unroll
        for (int j = 0; j < 8; ++j) acc[j] += bf2f(v0[j]) + bf2f(v1[j]);
    }
    if (i < end) {
        int s0 = csr_src[i];
        u16x8 v0 = *reinterpret_cast<const u16x8*>(&hs[(size_t)s0 * C + q * 8]);
        #pragma unroll
        for (int j = 0; j < 8; ++j) acc[j] += bf2f(v0[j]);
    }

    float w = dinv[node];
    float4 b0 = reinterpret_cast<const float4*>(b)[q * 2];
    float4 b1 = reinterpret_cast<const float4*>(b)[q * 2 + 1];
    float bb[8] = {b0.x, b0.y, b0.z, b0.w, b1.x, b1.y, b1.z, b1.w};
    u16x8 o;
    #pragma unroll
    for (int j = 0; j < 8; ++j) {
        float v = w * acc[j] + bb[j];
        if (RELU) v = fmaxf(v, 0.0f);
        o[j] = f2bf(v);
    }
    *reinterpret_cast<u16x8*>(&outp[(size_t)node * C + q * 8]) = o;
}

// ---------------- decoder: out[e] = sigmoid(dot(z[src[e]], z[dst[e]])) ----------------
// 8 lanes/edge, 16B bf16 loads, fp32 dot, shfl reduce.
__global__ __launch_bounds__(256) void k_decode(const int* __restrict__ esrc,
                                                const int* __restrict__ edst,
                                                const unsigned short* __restrict__ z,
                                                float* __restrict__ out) {
    int tid = threadIdx.x;
    int e = blockIdx.x * 32 + tid / 8;
    int q = tid % 8;
    if (e >= N_EDGES) return;
    int s = esrc[e], d = edst[e];
    u16x8 a = *reinterpret_cast<const u16x8*>(&z[(size_t)s * OUT_CH + q * 8]);
    u16x8 b = *reinterpret_cast<const u16x8*>(&z[(size_t)d * OUT_CH + q * 8]);
    float dot = 0.0f;
    #pragma unroll
    for (int j = 0; j < 8; ++j) dot += bf2f(a[j]) * bf2f(b[j]);
    dot += __shfl_xor(dot, 1);
    dot += __shfl_xor(dot, 2);
    dot += __shfl_xor(dot, 4);
    if (q == 0) out[e] = 1.0f / (1.0f + expf(-dot));
}

// ---------------- launch ----------------

extern "C" void kernel_launch(void* const* d_in, const int* in_sizes, int n_in,
                              void* d_out, int out_size, void* d_ws, size_t ws_size,
                              hipStream_t stream) {
    const float* x  = (const float*)d_in[0];
    const int*   ei = (const int*)d_in[1];
    const float* W1 = (const float*)d_in[2];
    const float* b1 = (const float*)d_in[3];
    const float* W2 = (const float*)d_in[4];
    const float* b2 = (const float*)d_in[5];
    float* out = (float*)d_out;

    const int* src = ei;
    const int* dst = ei + N_EDGES;

    // workspace layout (bytes)
    char* ws = (char*)d_ws;
    int*   deg     = (int*)(ws + 0);              // 400000
    int*   bcount  = (int*)(ws + 400000);         // 4096 (zeroed with deg: 101024 ints)
    int*   rowoff  = (int*)(ws + 0x80000);        // 400000
    int*   cursor  = (int*)(ws + 0x100000);       // 400000
    int*   bsums   = (int*)(ws + 0x180000);       // scan block sums
    int*   bcursor = (int*)(ws + 0x182000);       // 4096
    float* dinv    = (float*)(ws + 0x190000);     // 400000
    unsigned short* W1T = (unsigned short*)(ws + 0x200000);   // 64 KB
    unsigned short* W2T = (unsigned short*)(ws + 0x210000);   // 16 KB
    int*   csr_src = (int*)(ws + 0x220000);       // 6.4 MB
    int2*  bsorted = (int2*)(ws + 0x840000);      // 12.8 MB
    unsigned short* hs1 = (unsigned short*)(ws + 0x1800000);  // 25.6 MB
    unsigned short* h1r = (unsigned short*)(ws + 0x3200000);  // 25.6 MB
    unsigned short* hs2 = (unsigned short*)(ws + 0x4B00000);  // 12.8 MB
    unsigned short* z   = (unsigned short*)(ws + 0x5800000);  // 12.8 MB

    // --- norm + bucketed CSR build ---
    k_zero_int<<<(101024 + 255) / 256, 256, 0, stream>>>(deg, 101024);  // deg + bcount
    k_count2<<<(N_EDGES + 255) / 256, 256, 0, stream>>>(dst, deg, bcount);
    k_scan_block<<<NBLK_SCAN, 256, 0, stream>>>(deg, rowoff, bsums);
    k_scan_bsums<<<1, 512, 0, stream>>>(bsums);
    k_scan_add<<<NBLK_SCAN, 256, 0, stream>>>(rowoff, bsums);
    k_scan_buckets<<<1, NB_BUCKETS, 0, stream>>>(bcount, bcursor);
    k_dinv_cursor<<<(N_NODES + 255) / 256, 256, 0, stream>>>(deg, rowoff, dinv, cursor);
    k_bucket_scatter<<<(N_EDGES + 255) / 256, 256, 0, stream>>>(src, dst, bcursor, bsorted);
    k_fill_csr2<<<(N_EDGES + 255) / 256, 256, 0, stream>>>(bsorted, cursor, csr_src);

    // --- weight transpose+convert ---
    k_wt<IN_CH, HID_CH><<<(IN_CH * HID_CH + 255) / 256, 256, 0, stream>>>(W1, W1T);
    k_wt<HID_CH, OUT_CH><<<(HID_CH * OUT_CH + 255) / 256, 256, 0, stream>>>(W2, W2T);

    // --- layer 1 ---
    k_gemm1<<<(N_NODES + 63) / 64, 256, 0, stream>>>(x, W1T, dinv, hs1);
    k_gather_agg<HID_CH, true><<<(N_NODES * 16 + 255) / 256, 256, 0, stream>>>(
        rowoff, csr_src, hs1, dinv, b1, h1r);

    // --- layer 2 ---
    k_gemm2<<<(N_NODES + 63) / 64, 256, 0, stream>>>(h1r, W2T, dinv, hs2);
    k_gather_agg<OUT_CH, false><<<(N_NODES * 8 + 255) / 256, 256, 0, stream>>>(
        rowoff, csr_src, hs2, dinv, b2, z);

    // --- decoder ---
    k_decode<<<N_EDGES / 32, 256, 0, stream>>>(src, dst, z, out);
}

// Round 4
// 304.596 us; speedup vs baseline: 3.6851x; 3.6851x over previous
//
#include <hip/hip_runtime.h>
#include <math.h>

#define N_NODES 100000
#define N_EDGES 1600000
#define IN_CH 256
#define HID_CH 128
#define OUT_CH 64
#define NB 1024                      // buckets: node >> 7
#define NPART 256                    // partition blocks
#define EPB (N_EDGES / NPART)        // 6250 edges per partition block
#define NB_USED ((N_NODES + 127) / 128)  // 782 used buckets

typedef short s16x8 __attribute__((ext_vector_type(8)));
typedef unsigned short u16x8 __attribute__((ext_vector_type(8)));
typedef float f32x4 __attribute__((ext_vector_type(4)));

__device__ __forceinline__ float bf2f(unsigned short u) {
    union { unsigned int i; float f; } v;
    v.i = ((unsigned int)u) << 16;
    return v.f;
}
__device__ __forceinline__ unsigned short f2bf(float f) {
    union { float f; unsigned int i; } v;
    v.f = f;
    unsigned int u = v.i;
    return (unsigned short)((u + 0x7FFFu + ((u >> 16) & 1u)) >> 16);  // RNE
}

// ---------------- CSR build: LDS-histogram radix partition (no global atomics) ----------------

// P1: per-block LDS histogram of dst>>7 -> ghist[bucket*NPART + block]
__global__ __launch_bounds__(256) void k_hist(const int* __restrict__ dst,
                                              int* __restrict__ ghist) {
    __shared__ int h[NB];
    int b = blockIdx.x, t = threadIdx.x;
    for (int k = t; k < NB; k += 256) h[k] = 0;
    __syncthreads();
    int e0 = b * EPB;
    for (int e = e0 + t; e < e0 + EPB; e += 256)
        atomicAdd(&h[dst[e] >> 7], 1);
    __syncthreads();
    for (int k = t; k < NB; k += 256) ghist[k * NPART + b] = h[k];
}

// P2: per-bucket exclusive scan over the NPART blocks
__global__ __launch_bounds__(256) void k_scan_cols(const int* __restrict__ ghist,
                                                   int* __restrict__ goff,
                                                   int* __restrict__ btot) {
    __shared__ int tmp[NPART];
    int k = blockIdx.x, t = threadIdx.x;
    int v = ghist[k * NPART + t];
    tmp[t] = v;
    __syncthreads();
    for (int off = 1; off < NPART; off <<= 1) {
        int u = (t >= off) ? tmp[t - off] : 0;
        __syncthreads();
        tmp[t] += u;
        __syncthreads();
    }
    goff[k * NPART + t] = tmp[t] - v;
    if (t == NPART - 1) btot[k] = tmp[t];
}

// P2b: exclusive scan of bucket totals -> bbase[NB+1]
__global__ __launch_bounds__(1024) void k_scan_base(const int* __restrict__ btot,
                                                    int* __restrict__ bbase) {
    __shared__ int tmp[NB];
    int t = threadIdx.x;
    int v = btot[t];
    tmp[t] = v;
    __syncthreads();
    for (int off = 1; off < NB; off <<= 1) {
        int u = (t >= off) ? tmp[t - off] : 0;
        __syncthreads();
        tmp[t] += u;
        __syncthreads();
    }
    bbase[t] = tmp[t] - v;
    if (t == NB - 1) bbase[NB] = tmp[t];
}

// P3: partition edges into dst-bucket-sorted order; per-(bucket,block) ranges are
// pre-reserved and disjoint -> LDS cursors only, no global atomics.
__global__ __launch_bounds__(256) void k_partition(const int* __restrict__ src,
                                                   const int* __restrict__ dst,
                                                   const int* __restrict__ goff,
                                                   const int* __restrict__ bbase,
                                                   int2* __restrict__ bsorted) {
    __shared__ int cur[NB];
    int b = blockIdx.x, t = threadIdx.x;
    for (int k = t; k < NB; k += 256) cur[k] = bbase[k] + goff[k * NPART + b];
    __syncthreads();
    int e0 = b * EPB;
    for (int e = e0 + t; e < e0 + EPB; e += 256) {
        int s = src[e], d = dst[e];
        int pos = atomicAdd(&cur[d >> 7], 1);
        bsorted[pos] = make_int2(s, d);
    }
}

// P4: per-bucket (128 nodes, ~2048 edges): LDS count -> local scan -> rowoff/dinv,
// then fill csr_src (writes confined to this bucket's contiguous ~8KB region).
__global__ __launch_bounds__(256) void k_bucket_csr(const int2* __restrict__ bsorted,
                                                    const int* __restrict__ bbase,
                                                    int* __restrict__ rowoff,
                                                    float* __restrict__ dinv,
                                                    int* __restrict__ csr_src) {
    __shared__ int cnt[128];
    __shared__ int tmp[256];
    __shared__ int cur[128];
    int b = blockIdx.x, t = threadIdx.x;
    int ebeg = bbase[b], eend = bbase[b + 1];
    if (t < 128) cnt[t] = 0;
    __syncthreads();
    for (int e = ebeg + t; e < eend; e += 256)
        atomicAdd(&cnt[bsorted[e].y & 127], 1);
    __syncthreads();
    int v = (t < 128) ? cnt[t] : 0;
    tmp[t] = v;
    __syncthreads();
    for (int off = 1; off < 256; off <<= 1) {
        int u = (t >= off) ? tmp[t - off] : 0;
        __syncthreads();
        tmp[t] += u;
        __syncthreads();
    }
    if (t < 128) {
        int base = ebeg + tmp[t] - v;
        cur[t] = base;
        int node = b * 128 + t;
        if (node < N_NODES) {
            rowoff[node] = base;
            dinv[node] = rsqrtf((float)v + 1.0f);
        }
    }
    __syncthreads();
    for (int e = ebeg + t; e < eend; e += 256) {
        int2 ed = bsorted[e];
        int pos = atomicAdd(&cur[ed.y & 127], 1);
        csr_src[pos] = ed.x;
    }
}

// ---------------- W transpose+convert: WT[n][k] = bf16(W[k][n]) ----------------

template <int K, int N>
__global__ void k_wt(const float* __restrict__ W, unsigned short* __restrict__ WT) {
    int t = blockIdx.x * blockDim.x + threadIdx.x;
    if (t >= K * N) return;
    int n = t / K;
    int k = t % K;
    WT[t] = f2bf(W[(size_t)k * N + n]);
}

// ---------------- GEMM1: hs1[m][n] = bf16( dinv[m] * sum_k x[m][k] W1[k][n] ) ----------------
__global__ __launch_bounds__(256) void k_gemm1(const float* __restrict__ x,
                                               const unsigned short* __restrict__ W1T,
                                               const float* __restrict__ dinv,
                                               unsigned short* __restrict__ hs1) {
    int tid = threadIdx.x;
    int w = tid >> 6;
    int lane = tid & 63;
    int l15 = lane & 15;
    int lhi = lane >> 4;
    int m0 = blockIdx.x * 64 + w * 16;

    f32x4 acc[8] = {};

    int arow = m0 + l15;
    bool avalid = arow < N_NODES;
    const float* ap = x + (size_t)arow * IN_CH + lhi * 8;

    #pragma unroll
    for (int k0 = 0; k0 < IN_CH; k0 += 32) {
        s16x8 af = {};
        if (avalid) {
            float4 a0 = *reinterpret_cast<const float4*>(ap + k0);
            float4 a1 = *reinterpret_cast<const float4*>(ap + k0 + 4);
            af[0] = (short)f2bf(a0.x); af[1] = (short)f2bf(a0.y);
            af[2] = (short)f2bf(a0.z); af[3] = (short)f2bf(a0.w);
            af[4] = (short)f2bf(a1.x); af[5] = (short)f2bf(a1.y);
            af[6] = (short)f2bf(a1.z); af[7] = (short)f2bf(a1.w);
        }
        #pragma unroll
        for (int nt = 0; nt < 8; ++nt) {
            s16x8 bf = *reinterpret_cast<const s16x8*>(
                W1T + (size_t)(nt * 16 + l15) * IN_CH + k0 + lhi * 8);
            acc[nt] = __builtin_amdgcn_mfma_f32_16x16x32_bf16(af, bf, acc[nt], 0, 0, 0);
        }
    }

    float dv[4];
    int rb = m0 + lhi * 4;
    #pragma unroll
    for (int r = 0; r < 4; ++r) dv[r] = (rb + r < N_NODES) ? dinv[rb + r] : 0.0f;
    #pragma unroll
    for (int nt = 0; nt < 8; ++nt) {
        #pragma unroll
        for (int r = 0; r < 4; ++r) {
            int row = rb + r;
            if (row < N_NODES)
                hs1[(size_t)row * HID_CH + nt * 16 + l15] = f2bf(dv[r] * acc[nt][r]);
        }
    }
}

// ---------------- GEMM2: hs2[m][n] = bf16( dinv[m] * sum_k h1r[m][k] W2[k][n] ) ----------------
__global__ __launch_bounds__(256) void k_gemm2(const unsigned short* __restrict__ h1r,
                                               const unsigned short* __restrict__ W2T,
                                               const float* __restrict__ dinv,
                                               unsigned short* __restrict__ hs2) {
    int tid = threadIdx.x;
    int w = tid >> 6;
    int lane = tid & 63;
    int l15 = lane & 15;
    int lhi = lane >> 4;
    int m0 = blockIdx.x * 64 + w * 16;

    f32x4 acc[4] = {};

    int arow = m0 + l15;
    bool avalid = arow < N_NODES;
    const unsigned short* ap = h1r + (size_t)arow * HID_CH + lhi * 8;

    #pragma unroll
    for (int k0 = 0; k0 < HID_CH; k0 += 32) {
        s16x8 af = {};
        if (avalid) af = *reinterpret_cast<const s16x8*>(ap + k0);
        #pragma unroll
        for (int nt = 0; nt < 4; ++nt) {
            s16x8 bf = *reinterpret_cast<const s16x8*>(
                W2T + (size_t)(nt * 16 + l15) * HID_CH + k0 + lhi * 8);
            acc[nt] = __builtin_amdgcn_mfma_f32_16x16x32_bf16(af, bf, acc[nt], 0, 0, 0);
        }
    }

    float dv[4];
    int rb = m0 + lhi * 4;
    #pragma unroll
    for (int r = 0; r < 4; ++r) dv[r] = (rb + r < N_NODES) ? dinv[rb + r] : 0.0f;
    #pragma unroll
    for (int nt = 0; nt < 4; ++nt) {
        #pragma unroll
        for (int r = 0; r < 4; ++r) {
            int row = rb + r;
            if (row < N_NODES)
                hs2[(size_t)row * OUT_CH + nt * 16 + l15] = f2bf(dv[r] * acc[nt][r]);
        }
    }
}

// ---------------- gather aggregation (bf16 rows, fp32 accum) ----------------
template <int C, bool RELU>
__global__ __launch_bounds__(256) void k_gather_agg(const int* __restrict__ rowoff,
                                                    const int* __restrict__ csr_src,
                                                    const unsigned short* __restrict__ hs,
                                                    const float* __restrict__ dinv,
                                                    const float* __restrict__ b,
                                                    unsigned short* __restrict__ outp) {
    constexpr int TPN = C / 8;
    constexpr int NPB = 256 / TPN;
    int t = threadIdx.x;
    int node = blockIdx.x * NPB + t / TPN;
    int q = t % TPN;
    if (node >= N_NODES) return;

    int beg = rowoff[node];
    int end = (node + 1 < N_NODES) ? rowoff[node + 1] : N_EDGES;

    float acc[8];
    {
        u16x8 sv = *reinterpret_cast<const u16x8*>(&hs[(size_t)node * C + q * 8]);
        #pragma unroll
        for (int j = 0; j < 8; ++j) acc[j] = bf2f(sv[j]);
    }

    int i = beg;
    for (; i + 1 < end; i += 2) {
        int s0 = csr_src[i];
        int s1 = csr_src[i + 1];
        u16x8 v0 = *reinterpret_cast<const u16x8*>(&hs[(size_t)s0 * C + q * 8]);
        u16x8 v1 = *reinterpret_cast<const u16x8*>(&hs[(size_t)s1 * C + q * 8]);
        #pragma unroll
        for (int j = 0; j < 8; ++j) acc[j] += bf2f(v0[j]) + bf2f(v1[j]);
    }
    if (i < end) {
        int s0 = csr_src[i];
        u16x8 v0 = *reinterpret_cast<const u16x8*>(&hs[(size_t)s0 * C + q * 8]);
        #pragma unroll
        for (int j = 0; j < 8; ++j) acc[j] += bf2f(v0[j]);
    }

    float w = dinv[node];
    float4 b0 = reinterpret_cast<const float4*>(b)[q * 2];
    float4 b1 = reinterpret_cast<const float4*>(b)[q * 2 + 1];
    float bb[8] = {b0.x, b0.y, b0.z, b0.w, b1.x, b1.y, b1.z, b1.w};
    u16x8 o;
    #pragma unroll
    for (int j = 0; j < 8; ++j) {
        float v = w * acc[j] + bb[j];
        if (RELU) v = fmaxf(v, 0.0f);
        o[j] = f2bf(v);
    }
    *reinterpret_cast<u16x8*>(&outp[(size_t)node * C + q * 8]) = o;
}

// ---------------- decoder ----------------

__global__ __launch_bounds__(256) void k_decode(const int* __restrict__ esrc,
                                                const int* __restrict__ edst,
                                                const unsigned short* __restrict__ z,
                                                float* __restrict__ out) {
    int tid = threadIdx.x;
    int e = blockIdx.x * 32 + tid / 8;
    int q = tid % 8;
    if (e >= N_EDGES) return;
    int s = esrc[e], d = edst[e];
    u16x8 a = *reinterpret_cast<const u16x8*>(&z[(size_t)s * OUT_CH + q * 8]);
    u16x8 b = *reinterpret_cast<const u16x8*>(&z[(size_t)d * OUT_CH + q * 8]);
    float dot = 0.0f;
    #pragma unroll
    for (int j = 0; j < 8; ++j) dot += bf2f(a[j]) * bf2f(b[j]);
    dot += __shfl_xor(dot, 1);
    dot += __shfl_xor(dot, 2);
    dot += __shfl_xor(dot, 4);
    if (q == 0) out[e] = 1.0f / (1.0f + expf(-dot));
}

// ---------------- launch ----------------

extern "C" void kernel_launch(void* const* d_in, const int* in_sizes, int n_in,
                              void* d_out, int out_size, void* d_ws, size_t ws_size,
                              hipStream_t stream) {
    const float* x  = (const float*)d_in[0];
    const int*   ei = (const int*)d_in[1];
    const float* W1 = (const float*)d_in[2];
    const float* b1 = (const float*)d_in[3];
    const float* W2 = (const float*)d_in[4];
    const float* b2 = (const float*)d_in[5];
    float* out = (float*)d_out;

    const int* src = ei;
    const int* dst = ei + N_EDGES;

    // workspace layout (byte offsets)
    char* ws = (char*)d_ws;
    int*   ghist   = (int*)(ws + 0x000000);       // 1 MB (1024*256*4)
    int*   goff    = (int*)(ws + 0x100000);       // 1 MB
    int*   btot    = (int*)(ws + 0x200000);       // 4 KB
    int*   bbase   = (int*)(ws + 0x202000);       // 4.1 KB (1025 ints)
    int*   rowoff  = (int*)(ws + 0x210000);       // 400 KB
    float* dinv    = (float*)(ws + 0x290000);     // 400 KB
    unsigned short* W1T = (unsigned short*)(ws + 0x310000);   // 64 KB
    unsigned short* W2T = (unsigned short*)(ws + 0x320000);   // 16 KB
    int*   csr_src = (int*)(ws + 0x400000);       // 6.4 MB
    int2*  bsorted = (int2*)(ws + 0xC00000);      // 12.8 MB
    unsigned short* hs1 = (unsigned short*)(ws + 0x1900000);  // 25.6 MB
    unsigned short* h1r = (unsigned short*)(ws + 0x3200000);  // 25.6 MB
    unsigned short* hs2 = (unsigned short*)(ws + 0x4B00000);  // 12.8 MB
    unsigned short* z   = (unsigned short*)(ws + 0x5800000);  // 12.8 MB

    // --- CSR build (no global atomics) ---
    k_hist<<<NPART, 256, 0, stream>>>(dst, ghist);
    k_scan_cols<<<NB, 256, 0, stream>>>(ghist, goff, btot);
    k_scan_base<<<1, NB, 0, stream>>>(btot, bbase);
    k_partition<<<NPART, 256, 0, stream>>>(src, dst, goff, bbase, bsorted);
    k_bucket_csr<<<NB_USED, 256, 0, stream>>>(bsorted, bbase, rowoff, dinv, csr_src);

    // --- weight transpose+convert ---
    k_wt<IN_CH, HID_CH><<<(IN_CH * HID_CH + 255) / 256, 256, 0, stream>>>(W1, W1T);
    k_wt<HID_CH, OUT_CH><<<(HID_CH * OUT_CH + 255) / 256, 256, 0, stream>>>(W2, W2T);

    // --- layer 1 ---
    k_gemm1<<<(N_NODES + 63) / 64, 256, 0, stream>>>(x, W1T, dinv, hs1);
    k_gather_agg<HID_CH, true><<<(N_NODES * 16 + 255) / 256, 256, 0, stream>>>(
        rowoff, csr_src, hs1, dinv, b1, h1r);

    // --- layer 2 ---
    k_gemm2<<<(N_NODES + 63) / 64, 256, 0, stream>>>(h1r, W2T, dinv, hs2);
    k_gather_agg<OUT_CH, false><<<(N_NODES * 8 + 255) / 256, 256, 0, stream>>>(
        rowoff, csr_src, hs2, dinv, b2, z);

    // --- decoder ---
    k_decode<<<N_EDGES / 32, 256, 0, stream>>>(src, dst, z, out);
}

// Round 5
// 292.000 us; speedup vs baseline: 3.8441x; 1.0431x over previous
//
#include <hip/hip_runtime.h>
#include <math.h>

#define N_NODES 100000
#define N_EDGES 1600000
#define IN_CH 256
#define HID_CH 128
#define OUT_CH 64
#define NB 1024                      // buckets: node >> 7
#define NPART 256                    // partition blocks
#define EPB (N_EDGES / NPART)        // 6250 edges per partition block
#define NB_USED ((N_NODES + 127) / 128)  // 782 used buckets

typedef short s16x8 __attribute__((ext_vector_type(8)));
typedef unsigned short u16x8 __attribute__((ext_vector_type(8)));
typedef float f32x4 __attribute__((ext_vector_type(4)));

__device__ __forceinline__ float bf2f(unsigned short u) {
    union { unsigned int i; float f; } v;
    v.i = ((unsigned int)u) << 16;
    return v.f;
}
__device__ __forceinline__ unsigned short f2bf(float f) {
    union { float f; unsigned int i; } v;
    v.f = f;
    unsigned int u = v.i;
    return (unsigned short)((u + 0x7FFFu + ((u >> 16) & 1u)) >> 16);  // RNE
}

// ---------------- CSR build: LDS-histogram radix partition (no global atomics) ----------------

__global__ __launch_bounds__(256) void k_hist(const int* __restrict__ dst,
                                              int* __restrict__ ghist) {
    __shared__ int h[NB];
    int b = blockIdx.x, t = threadIdx.x;
    for (int k = t; k < NB; k += 256) h[k] = 0;
    __syncthreads();
    int e0 = b * EPB;
    for (int e = e0 + t; e < e0 + EPB; e += 256)
        atomicAdd(&h[dst[e] >> 7], 1);
    __syncthreads();
    for (int k = t; k < NB; k += 256) ghist[k * NPART + b] = h[k];
}

__global__ __launch_bounds__(256) void k_scan_cols(const int* __restrict__ ghist,
                                                   int* __restrict__ goff,
                                                   int* __restrict__ btot) {
    __shared__ int tmp[NPART];
    int k = blockIdx.x, t = threadIdx.x;
    int v = ghist[k * NPART + t];
    tmp[t] = v;
    __syncthreads();
    for (int off = 1; off < NPART; off <<= 1) {
        int u = (t >= off) ? tmp[t - off] : 0;
        __syncthreads();
        tmp[t] += u;
        __syncthreads();
    }
    goff[k * NPART + t] = tmp[t] - v;
    if (t == NPART - 1) btot[k] = tmp[t];
}

__global__ __launch_bounds__(1024) void k_scan_base(const int* __restrict__ btot,
                                                    int* __restrict__ bbase) {
    __shared__ int tmp[NB];
    int t = threadIdx.x;
    int v = btot[t];
    tmp[t] = v;
    __syncthreads();
    for (int off = 1; off < NB; off <<= 1) {
        int u = (t >= off) ? tmp[t - off] : 0;
        __syncthreads();
        tmp[t] += u;
        __syncthreads();
    }
    bbase[t] = tmp[t] - v;
    if (t == NB - 1) bbase[NB] = tmp[t];
}

__global__ __launch_bounds__(256) void k_partition(const int* __restrict__ src,
                                                   const int* __restrict__ dst,
                                                   const int* __restrict__ goff,
                                                   const int* __restrict__ bbase,
                                                   int2* __restrict__ bsorted) {
    __shared__ int cur[NB];
    int b = blockIdx.x, t = threadIdx.x;
    for (int k = t; k < NB; k += 256) cur[k] = bbase[k] + goff[k * NPART + b];
    __syncthreads();
    int e0 = b * EPB;
    for (int e = e0 + t; e < e0 + EPB; e += 256) {
        int s = src[e], d = dst[e];
        int pos = atomicAdd(&cur[d >> 7], 1);
        bsorted[pos] = make_int2(s, d);
    }
}

__global__ __launch_bounds__(256) void k_bucket_csr(const int2* __restrict__ bsorted,
                                                    const int* __restrict__ bbase,
                                                    int* __restrict__ rowoff,
                                                    float* __restrict__ dinv,
                                                    int* __restrict__ csr_src) {
    __shared__ int cnt[128];
    __shared__ int tmp[256];
    __shared__ int cur[128];
    int b = blockIdx.x, t = threadIdx.x;
    int ebeg = bbase[b], eend = bbase[b + 1];
    if (t < 128) cnt[t] = 0;
    __syncthreads();
    for (int e = ebeg + t; e < eend; e += 256)
        atomicAdd(&cnt[bsorted[e].y & 127], 1);
    __syncthreads();
    int v = (t < 128) ? cnt[t] : 0;
    tmp[t] = v;
    __syncthreads();
    for (int off = 1; off < 256; off <<= 1) {
        int u = (t >= off) ? tmp[t - off] : 0;
        __syncthreads();
        tmp[t] += u;
        __syncthreads();
    }
    if (t < 128) {
        int base = ebeg + tmp[t] - v;
        cur[t] = base;
        int node = b * 128 + t;
        if (node < N_NODES) {
            rowoff[node] = base;
            dinv[node] = rsqrtf((float)v + 1.0f);
        }
    }
    __syncthreads();
    for (int e = ebeg + t; e < eend; e += 256) {
        int2 ed = bsorted[e];
        int pos = atomicAdd(&cur[ed.y & 127], 1);
        csr_src[pos] = ed.x;
    }
}

// ---------------- W transpose+convert: WT[n][k] = bf16(W[k][n]) ----------------

template <int K, int N>
__global__ void k_wt(const float* __restrict__ W, unsigned short* __restrict__ WT) {
    int t = blockIdx.x * blockDim.x + threadIdx.x;
    if (t >= K * N) return;
    int n = t / K;
    int k = t % K;
    WT[t] = f2bf(W[(size_t)k * N + n]);
}

// ---------------- GEMM1: hs1[m][n] = bf16( dinv[m] * sum_k x[m][k] W1[k][n] ) ----------------
// Branch-free clamped rows; full-K upfront A loads (16 float4 in flight per wave).
__global__ __launch_bounds__(256) void k_gemm1(const float* __restrict__ x,
                                               const unsigned short* __restrict__ W1T,
                                               const float* __restrict__ dinv,
                                               unsigned short* __restrict__ hs1) {
    int tid = threadIdx.x;
    int w = tid >> 6;
    int lane = tid & 63;
    int l15 = lane & 15;
    int lhi = lane >> 4;
    int m0 = blockIdx.x * 64 + w * 16;

    int arow = m0 + l15;
    int arowc = (arow < N_NODES) ? arow : (N_NODES - 1);  // clamp: branch-free loads
    const float4* ap = reinterpret_cast<const float4*>(x + (size_t)arowc * IN_CH) + lhi * 2;

    // issue ALL A loads upfront (full K=256 panel for this wave's 16 rows)
    float4 a[16];
    #pragma unroll
    for (int kk = 0; kk < 8; ++kk) {
        a[2 * kk]     = ap[kk * 8];
        a[2 * kk + 1] = ap[kk * 8 + 1];
    }
    // convert to bf16 fragments
    s16x8 af[8];
    #pragma unroll
    for (int kk = 0; kk < 8; ++kk) {
        float4 a0 = a[2 * kk], a1 = a[2 * kk + 1];
        af[kk][0] = (short)f2bf(a0.x); af[kk][1] = (short)f2bf(a0.y);
        af[kk][2] = (short)f2bf(a0.z); af[kk][3] = (short)f2bf(a0.w);
        af[kk][4] = (short)f2bf(a1.x); af[kk][5] = (short)f2bf(a1.y);
        af[kk][6] = (short)f2bf(a1.z); af[kk][7] = (short)f2bf(a1.w);
    }

    f32x4 acc[8] = {};
    #pragma unroll
    for (int kk = 0; kk < 8; ++kk) {
        #pragma unroll
        for (int nt = 0; nt < 8; ++nt) {
            s16x8 bf = *reinterpret_cast<const s16x8*>(
                W1T + (size_t)(nt * 16 + l15) * IN_CH + kk * 32 + lhi * 8);
            acc[nt] = __builtin_amdgcn_mfma_f32_16x16x32_bf16(af[kk], bf, acc[nt], 0, 0, 0);
        }
    }

    float dv[4];
    int rb = m0 + lhi * 4;
    #pragma unroll
    for (int r = 0; r < 4; ++r) dv[r] = (rb + r < N_NODES) ? dinv[rb + r] : 0.0f;
    #pragma unroll
    for (int nt = 0; nt < 8; ++nt) {
        #pragma unroll
        for (int r = 0; r < 4; ++r) {
            int row = rb + r;
            if (row < N_NODES)
                hs1[(size_t)row * HID_CH + nt * 16 + l15] = f2bf(dv[r] * acc[nt][r]);
        }
    }
}

// ---------------- GEMM2: hs2[m][n] = bf16( dinv[m] * sum_k h1r[m][k] W2[k][n] ) ----------------
__global__ __launch_bounds__(256) void k_gemm2(const unsigned short* __restrict__ h1r,
                                               const unsigned short* __restrict__ W2T,
                                               const float* __restrict__ dinv,
                                               unsigned short* __restrict__ hs2) {
    int tid = threadIdx.x;
    int w = tid >> 6;
    int lane = tid & 63;
    int l15 = lane & 15;
    int lhi = lane >> 4;
    int m0 = blockIdx.x * 64 + w * 16;

    int arow = m0 + l15;
    int arowc = (arow < N_NODES) ? arow : (N_NODES - 1);
    const s16x8* ap = reinterpret_cast<const s16x8*>(h1r + (size_t)arowc * HID_CH) + lhi;

    // upfront A loads (full K=128)
    s16x8 af[4];
    #pragma unroll
    for (int kk = 0; kk < 4; ++kk) af[kk] = ap[kk * 4];

    f32x4 acc[4] = {};
    #pragma unroll
    for (int kk = 0; kk < 4; ++kk) {
        #pragma unroll
        for (int nt = 0; nt < 4; ++nt) {
            s16x8 bf = *reinterpret_cast<const s16x8*>(
                W2T + (size_t)(nt * 16 + l15) * HID_CH + kk * 32 + lhi * 8);
            acc[nt] = __builtin_amdgcn_mfma_f32_16x16x32_bf16(af[kk], bf, acc[nt], 0, 0, 0);
        }
    }

    float dv[4];
    int rb = m0 + lhi * 4;
    #pragma unroll
    for (int r = 0; r < 4; ++r) dv[r] = (rb + r < N_NODES) ? dinv[rb + r] : 0.0f;
    #pragma unroll
    for (int nt = 0; nt < 4; ++nt) {
        #pragma unroll
        for (int r = 0; r < 4; ++r) {
            int row = rb + r;
            if (row < N_NODES)
                hs2[(size_t)row * OUT_CH + nt * 16 + l15] = f2bf(dv[r] * acc[nt][r]);
        }
    }
}

// ---------------- gather aggregation (bf16 rows, fp32 accum) ----------------
template <int C, bool RELU>
__global__ __launch_bounds__(256) void k_gather_agg(const int* __restrict__ rowoff,
                                                    const int* __restrict__ csr_src,
                                                    const unsigned short* __restrict__ hs,
                                                    const float* __restrict__ dinv,
                                                    const float* __restrict__ b,
                                                    unsigned short* __restrict__ outp) {
    constexpr int TPN = C / 8;
    constexpr int NPB = 256 / TPN;
    int t = threadIdx.x;
    int node = blockIdx.x * NPB + t / TPN;
    int q = t % TPN;
    if (node >= N_NODES) return;

    int beg = rowoff[node];
    int end = (node + 1 < N_NODES) ? rowoff[node + 1] : N_EDGES;

    float acc[8];
    {
        u16x8 sv = *reinterpret_cast<const u16x8*>(&hs[(size_t)node * C + q * 8]);
        #pragma unroll
        for (int j = 0; j < 8; ++j) acc[j] = bf2f(sv[j]);
    }

    int i = beg;
    for (; i + 1 < end; i += 2) {
        int s0 = csr_src[i];
        int s1 = csr_src[i + 1];
        u16x8 v0 = *reinterpret_cast<const u16x8*>(&hs[(size_t)s0 * C + q * 8]);
        u16x8 v1 = *reinterpret_cast<const u16x8*>(&hs[(size_t)s1 * C + q * 8]);
        #pragma unroll
        for (int j = 0; j < 8; ++j) acc[j] += bf2f(v0[j]) + bf2f(v1[j]);
    }
    if (i < end) {
        int s0 = csr_src[i];
        u16x8 v0 = *reinterpret_cast<const u16x8*>(&hs[(size_t)s0 * C + q * 8]);
        #pragma unroll
        for (int j = 0; j < 8; ++j) acc[j] += bf2f(v0[j]);
    }

    float w = dinv[node];
    float4 b0 = reinterpret_cast<const float4*>(b)[q * 2];
    float4 b1 = reinterpret_cast<const float4*>(b)[q * 2 + 1];
    float bb[8] = {b0.x, b0.y, b0.z, b0.w, b1.x, b1.y, b1.z, b1.w};
    u16x8 o;
    #pragma unroll
    for (int j = 0; j < 8; ++j) {
        float v = w * acc[j] + bb[j];
        if (RELU) v = fmaxf(v, 0.0f);
        o[j] = f2bf(v);
    }
    *reinterpret_cast<u16x8*>(&outp[(size_t)node * C + q * 8]) = o;
}

// ---------------- decoder ----------------

__global__ __launch_bounds__(256) void k_decode(const int* __restrict__ esrc,
                                                const int* __restrict__ edst,
                                                const unsigned short* __restrict__ z,
                                                float* __restrict__ out) {
    int tid = threadIdx.x;
    int e = blockIdx.x * 32 + tid / 8;
    int q = tid % 8;
    if (e >= N_EDGES) return;
    int s = esrc[e], d = edst[e];
    u16x8 a = *reinterpret_cast<const u16x8*>(&z[(size_t)s * OUT_CH + q * 8]);
    u16x8 b = *reinterpret_cast<const u16x8*>(&z[(size_t)d * OUT_CH + q * 8]);
    float dot = 0.0f;
    #pragma unroll
    for (int j = 0; j < 8; ++j) dot += bf2f(a[j]) * bf2f(b[j]);
    dot += __shfl_xor(dot, 1);
    dot += __shfl_xor(dot, 2);
    dot += __shfl_xor(dot, 4);
    if (q == 0) out[e] = 1.0f / (1.0f + expf(-dot));
}

// ---------------- launch ----------------

extern "C" void kernel_launch(void* const* d_in, const int* in_sizes, int n_in,
                              void* d_out, int out_size, void* d_ws, size_t ws_size,
                              hipStream_t stream) {
    const float* x  = (const float*)d_in[0];
    const int*   ei = (const int*)d_in[1];
    const float* W1 = (const float*)d_in[2];
    const float* b1 = (const float*)d_in[3];
    const float* W2 = (const float*)d_in[4];
    const float* b2 = (const float*)d_in[5];
    float* out = (float*)d_out;

    const int* src = ei;
    const int* dst = ei + N_EDGES;

    // workspace layout (byte offsets)
    char* ws = (char*)d_ws;
    int*   ghist   = (int*)(ws + 0x000000);       // 1 MB
    int*   goff    = (int*)(ws + 0x100000);       // 1 MB
    int*   btot    = (int*)(ws + 0x200000);       // 4 KB
    int*   bbase   = (int*)(ws + 0x202000);       // 4.1 KB
    int*   rowoff  = (int*)(ws + 0x210000);       // 400 KB
    float* dinv    = (float*)(ws + 0x290000);     // 400 KB
    unsigned short* W1T = (unsigned short*)(ws + 0x310000);   // 64 KB
    unsigned short* W2T = (unsigned short*)(ws + 0x320000);   // 16 KB
    int*   csr_src = (int*)(ws + 0x400000);       // 6.4 MB
    int2*  bsorted = (int2*)(ws + 0xC00000);      // 12.8 MB
    unsigned short* hs1 = (unsigned short*)(ws + 0x1900000);  // 25.6 MB
    unsigned short* h1r = (unsigned short*)(ws + 0x3200000);  // 25.6 MB
    unsigned short* hs2 = (unsigned short*)(ws + 0x4B00000);  // 12.8 MB
    unsigned short* z   = (unsigned short*)(ws + 0x5800000);  // 12.8 MB

    // --- CSR build (no global atomics) ---
    k_hist<<<NPART, 256, 0, stream>>>(dst, ghist);
    k_scan_cols<<<NB, 256, 0, stream>>>(ghist, goff, btot);
    k_scan_base<<<1, NB, 0, stream>>>(btot, bbase);
    k_partition<<<NPART, 256, 0, stream>>>(src, dst, goff, bbase, bsorted);
    k_bucket_csr<<<NB_USED, 256, 0, stream>>>(bsorted, bbase, rowoff, dinv, csr_src);

    // --- weight transpose+convert ---
    k_wt<IN_CH, HID_CH><<<(IN_CH * HID_CH + 255) / 256, 256, 0, stream>>>(W1, W1T);
    k_wt<HID_CH, OUT_CH><<<(HID_CH * OUT_CH + 255) / 256, 256, 0, stream>>>(W2, W2T);

    // --- layer 1 ---
    k_gemm1<<<(N_NODES + 63) / 64, 256, 0, stream>>>(x, W1T, dinv, hs1);
    k_gather_agg<HID_CH, true><<<(N_NODES * 16 + 255) / 256, 256, 0, stream>>>(
        rowoff, csr_src, hs1, dinv, b1, h1r);

    // --- layer 2 ---
    k_gemm2<<<(N_NODES + 63) / 64, 256, 0, stream>>>(h1r, W2T, dinv, hs2);
    k_gather_agg<OUT_CH, false><<<(N_NODES * 8 + 255) / 256, 256, 0, stream>>>(
        rowoff, csr_src, hs2, dinv, b2, z);

    // --- decoder ---
    k_decode<<<N_EDGES / 32, 256, 0, stream>>>(src, dst, z, out);
}